// Round 1
// baseline (5652.045 us; speedup 1.0000x reference)
//
#include <hip/hip_runtime.h>

// SelfEquiConv: E=100000, S=64, V=32.
// Factorization:
//   P[e,(u,v)] = s1[u]*s2[v]                (4096)  } K-vector, scale folded per K-part
//   Q[e,(u,v)] = sum_i v1[u,i]*v2[v,i]      (1024)  }
//   [z_s|z_g][e,n] = sum_k A_k * K[e,k] * B[k,n]   (B = reshaped w_ss_*/w_vv_*)
//   R[e,(v,w)] = A_SV * s1 @ w_sv_v ;  z_sv[w,i] = sum_v R[v,w]*v2[v,i]
//   U[e,(u,w)] = A_SV * s2 @ w_vs_v ;  z_vs[w,i] = sum_u U[u,w]*v1[u,i]
// Epilogue: silu(z_s)@wl_s*S^-0.5 ; (sigmoid(z_g)*z_v)@wl_v*V^-0.5.

constexpr float A_SS  = 0.011048543456039806f; // (2*64*64)^-0.5   == A_SS_G
constexpr float A_VV  = 0.012757759747374832f; // (2*32*32*3)^-0.5 == A_VV_G
constexpr float A_SV  = 0.009021097956087904f; // (2*64*32*3)^-0.5 == A_VS_V
constexpr float SO_SC = 0.125f;                // 64^-0.5
constexpr float VO_SC = 0.1767766952966369f;   // 32^-0.5

__global__ __launch_bounds__(256, 2)
void seconv_f32(const float* __restrict__ fea1,
                const float* __restrict__ fea2,
                const float* __restrict__ wss_s,   // (64,64,64)
                const float* __restrict__ wvv_s,   // (32,32,64)
                const float* __restrict__ wss_g,   // (64,64,32)
                const float* __restrict__ wvv_g,   // (32,32,32)
                const float* __restrict__ wsv,     // (64,32,32)
                const float* __restrict__ wvs,     // (32,64,32)
                const float* __restrict__ wls,     // (64,64)
                const float* __restrict__ wlv,     // (32,32)
                float* __restrict__ out,
                int E)
{
    __shared__ float s1L[16][64];
    __shared__ float s2L[16][64];
    __shared__ float v1L[16][96];
    __shared__ float v2L[16][96];
    __shared__ float zS [16][64];
    __shared__ float zG [16][32];
    __shared__ float zVb[16][96];
    __shared__ float RB [8][1024];   // reused: R then U, 8 edges per pass

    const int tid   = threadIdx.x;
    const int lane  = tid & 63;
    const int wv    = tid >> 6;
    const int laneg = lane & 31;
    const int e0    = blockIdx.x * 16;

    // ---- stage inputs (edge index clamped; E=100000 is divisible by 16 anyway) ----
    for (int i = tid; i < 16 * 160; i += 256) {
        int e = i / 160, c = i - e * 160;
        int ge = e0 + e; if (ge >= E) ge = E - 1;
        float a = fea1[ge * 160 + c];
        float b = fea2[ge * 160 + c];
        if (c < 64) { s1L[e][c] = a;      s2L[e][c] = b; }
        else        { v1L[e][c - 64] = a; v2L[e][c - 64] = b; }
    }
    __syncthreads();

    // ---- main bilinear GEMM: z_s[64] + z_g[32] for this wave's 4 edges ----
    const int eb = wv * 4;
    float accS[4] = {0.f, 0.f, 0.f, 0.f};
    float accG[4] = {0.f, 0.f, 0.f, 0.f};

    // scalar-scalar part: k = u*64+v  (2 u's per inner pass to share s2 reads)
    for (int u = 0; u < 64; u += 2) {
        float a1[2][4];
        #pragma unroll
        for (int j = 0; j < 4; ++j) {
            a1[0][j] = A_SS * s1L[eb + j][u];
            a1[1][j] = A_SS * s1L[eb + j][u + 1];
        }
        for (int v = 0; v < 64; ++v) {
            int k0 = u * 64 + v;
            int k1 = k0 + 64;
            float wS0 = wss_s[k0 * 64 + lane];
            float wS1 = wss_s[k1 * 64 + lane];
            float wG0 = wss_g[k0 * 32 + laneg];
            float wG1 = wss_g[k1 * 32 + laneg];
            #pragma unroll
            for (int j = 0; j < 4; ++j) {
                float s2v = s2L[eb + j][v];
                float x0 = a1[0][j] * s2v;
                float x1 = a1[1][j] * s2v;
                accS[j] = fmaf(x0, wS0, accS[j]);
                accS[j] = fmaf(x1, wS1, accS[j]);
                accG[j] = fmaf(x0, wG0, accG[j]);
                accG[j] = fmaf(x1, wG1, accG[j]);
            }
        }
    }

    // vector-vector part: k' = u*32+v, A-element is a 3-dot
    for (int u = 0; u < 32; u += 2) {
        float b1[2][4][3];
        #pragma unroll
        for (int j = 0; j < 4; ++j)
            #pragma unroll
            for (int i3 = 0; i3 < 3; ++i3) {
                b1[0][j][i3] = A_VV * v1L[eb + j][u * 3 + i3];
                b1[1][j][i3] = A_VV * v1L[eb + j][(u + 1) * 3 + i3];
            }
        for (int v = 0; v < 32; ++v) {
            int k0 = u * 32 + v;
            int k1 = k0 + 32;
            float wS0 = wvv_s[k0 * 64 + lane];
            float wS1 = wvv_s[k1 * 64 + lane];
            float wG0 = wvv_g[k0 * 32 + laneg];
            float wG1 = wvv_g[k1 * 32 + laneg];
            #pragma unroll
            for (int j = 0; j < 4; ++j) {
                float c0 = v2L[eb + j][v * 3 + 0];
                float c1 = v2L[eb + j][v * 3 + 1];
                float c2 = v2L[eb + j][v * 3 + 2];
                float x0 = b1[0][j][0] * c0;
                x0 = fmaf(b1[0][j][1], c1, x0);
                x0 = fmaf(b1[0][j][2], c2, x0);
                float x1 = b1[1][j][0] * c0;
                x1 = fmaf(b1[1][j][1], c1, x1);
                x1 = fmaf(b1[1][j][2], c2, x1);
                accS[j] = fmaf(x0, wS0, accS[j]);
                accS[j] = fmaf(x1, wS1, accS[j]);
                accG[j] = fmaf(x0, wG0, accG[j]);
                accG[j] = fmaf(x1, wG1, accG[j]);
            }
        }
    }

    #pragma unroll
    for (int j = 0; j < 4; ++j) {
        zS[eb + j][lane] = accS[j];
        if (lane < 32) zG[eb + j][lane] = accG[j];
    }
    __syncthreads();

    // ---- R/U + z_v, block-cooperative, 8 edges per pass ----
    for (int g = 0; g < 2; ++g) {
        const int ebase = g * 8;

        // R[e][v*32+w] = A_SV * sum_u s1[e][u] * wsv[u*1024 + (v*32+w)]
        {
            float r[4][8];
            #pragma unroll
            for (int p = 0; p < 4; ++p)
                #pragma unroll
                for (int j = 0; j < 8; ++j) r[p][j] = 0.f;
            for (int u = 0; u < 64; ++u) {
                float wr[4];
                #pragma unroll
                for (int p = 0; p < 4; ++p) wr[p] = wsv[u * 1024 + p * 256 + tid];
                float s1v[8];
                #pragma unroll
                for (int j = 0; j < 8; ++j) s1v[j] = s1L[ebase + j][u];
                #pragma unroll
                for (int p = 0; p < 4; ++p)
                    #pragma unroll
                    for (int j = 0; j < 8; ++j)
                        r[p][j] = fmaf(s1v[j], wr[p], r[p][j]);
            }
            #pragma unroll
            for (int p = 0; p < 4; ++p)
                #pragma unroll
                for (int j = 0; j < 8; ++j)
                    RB[j][p * 256 + tid] = A_SV * r[p][j];
        }
        __syncthreads();

        // z_sv: zVb[e][w*3+i] = sum_v RB[e][v*32+w] * v2[e][v*3+i]
        for (int i = tid; i < 8 * 96; i += 256) {
            int e8 = i / 96, t = i - e8 * 96;
            int w = t / 3, i3 = t - w * 3;
            float acc = 0.f;
            #pragma unroll
            for (int v = 0; v < 32; ++v)
                acc = fmaf(RB[e8][v * 32 + w], v2L[ebase + e8][v * 3 + i3], acc);
            zVb[ebase + e8][t] = acc;
        }
        __syncthreads();

        // U[e][u*32+w] = A_SV * sum_v s2[e][v] * wvs[u*2048 + v*32 + w]
        {
            float r[4][8];
            #pragma unroll
            for (int p = 0; p < 4; ++p)
                #pragma unroll
                for (int j = 0; j < 8; ++j) r[p][j] = 0.f;
            int cb[4];
            #pragma unroll
            for (int p = 0; p < 4; ++p) {
                int t = p * 256 + tid;
                cb[p] = (t >> 5) * 2048 + (t & 31);
            }
            for (int v = 0; v < 64; ++v) {
                float wr[4];
                #pragma unroll
                for (int p = 0; p < 4; ++p) wr[p] = wvs[cb[p] + v * 32];
                float s2v[8];
                #pragma unroll
                for (int j = 0; j < 8; ++j) s2v[j] = s2L[ebase + j][v];
                #pragma unroll
                for (int p = 0; p < 4; ++p)
                    #pragma unroll
                    for (int j = 0; j < 8; ++j)
                        r[p][j] = fmaf(s2v[j], wr[p], r[p][j]);
            }
            #pragma unroll
            for (int p = 0; p < 4; ++p)
                #pragma unroll
                for (int j = 0; j < 8; ++j)
                    RB[j][p * 256 + tid] = A_SV * r[p][j];
        }
        __syncthreads();

        // z_vs add: zVb[e][w*3+i] += sum_u RB[e][u*32+w] * v1[e][u*3+i]
        for (int i = tid; i < 8 * 96; i += 256) {
            int e8 = i / 96, t = i - e8 * 96;
            int w = t / 3, i3 = t - w * 3;
            float acc = zVb[ebase + e8][t];
            #pragma unroll
            for (int u = 0; u < 32; ++u)
                acc = fmaf(RB[e8][u * 32 + w], v1L[ebase + e8][u * 3 + i3], acc);
            zVb[ebase + e8][t] = acc;
        }
        __syncthreads();
    }

    // ---- activations (in place) ----
    for (int i = tid; i < 16 * 64; i += 256) {
        int e = i >> 6, w = i & 63;
        float z = zS[e][w];
        zS[e][w] = z / (1.f + __expf(-z));          // silu
    }
    for (int i = tid; i < 16 * 96; i += 256) {
        int e = i / 96, t = i - e * 96;
        float zg = zG[e][t / 3];
        float sg = 1.f / (1.f + __expf(-zg));       // sigmoid gate
        zVb[e][t] *= sg;
    }
    __syncthreads();

    // ---- output linear layers ----
    for (int i = tid; i < 16 * 64; i += 256) {
        int e = i >> 6, wo = i & 63;
        int ge = e0 + e;
        float acc = 0.f;
        #pragma unroll 8
        for (int w = 0; w < 64; ++w)
            acc = fmaf(zS[e][w], wls[w * 64 + wo], acc);
        if (ge < E) out[ge * 160 + wo] = SO_SC * acc;
    }
    for (int i = tid; i < 16 * 96; i += 256) {
        int e = i / 96, t = i - e * 96;
        int wo = t / 3, i3 = t - wo * 3;
        int ge = e0 + e;
        float acc = 0.f;
        #pragma unroll 8
        for (int v = 0; v < 32; ++v)
            acc = fmaf(zVb[e][v * 3 + i3], wlv[v * 32 + wo], acc);
        if (ge < E) out[ge * 160 + 64 + t] = VO_SC * acc;
    }
}

extern "C" void kernel_launch(void* const* d_in, const int* in_sizes, int n_in,
                              void* d_out, int out_size, void* d_ws, size_t ws_size,
                              hipStream_t stream) {
    const float* fea1  = (const float*)d_in[0];
    const float* fea2  = (const float*)d_in[1];
    // d_in[2] fea_weight, d_in[3] batch_edge: unused by the reference
    const float* wss_s = (const float*)d_in[4];
    const float* wvv_s = (const float*)d_in[5];
    const float* wss_g = (const float*)d_in[6];
    const float* wvv_g = (const float*)d_in[7];
    const float* wsv   = (const float*)d_in[8];
    const float* wvs   = (const float*)d_in[9];
    const float* wls   = (const float*)d_in[10];
    const float* wlv   = (const float*)d_in[11];
    float* out = (float*)d_out;

    int E = in_sizes[0] / 160;           // 100000
    int grid = (E + 15) / 16;            // 6250
    seconv_f32<<<dim3(grid), dim3(256), 0, stream>>>(
        fea1, fea2, wss_s, wvv_s, wss_g, wvv_g, wsv, wvs, wls, wlv, out, E);
}

// Round 2
// 694.881 us; speedup vs baseline: 8.1338x; 8.1338x over previous
//
#include <hip/hip_runtime.h>

// SelfEquiConv E=100000, S=64, V=32 — bf16 MFMA formulation.
// G1: [z_s|z_g] = A1 @ B1,  A1[e,k] = {A_SS*s1[u]s2[v] | A_VV*sum_i v1[u,i]v2[v,i]}, K=5120, N=96
// G2: z_v       = A2 @ B2,  A2[(e,i),k] = {s1[u]*v2[v,i] | v1[u,i]*s2[v]},          K=4096, N=32
// Weights pre-swizzled (prep kernel) into MFMA B-fragment order, scales folded in.
// Epilogue (silu/sigmoid gate + wl_s/wl_v) in fp32 VALU, validated in round 1.

typedef __bf16 bf16x8 __attribute__((ext_vector_type(8)));
typedef float  f32x4  __attribute__((ext_vector_type(4)));

constexpr float A_SS  = 0.011048543456039806f; // (2*64*64)^-0.5  == A_SS_G
constexpr float A_VV  = 0.012757759747374832f; // (2*32*32*3)^-0.5 == A_VV_G
constexpr float A_SV  = 0.009021097956087904f; // (2*64*32*3)^-0.5 == A_VS_V

#define MFMA16(A, B, C) __builtin_amdgcn_mfma_f32_16x16x32_bf16((A), (B), (C), 0, 0, 0)

// ---------------- prep: swizzle weights into MFMA B-fragment order ----------------
// B1p: [160 kchunks][6 ntiles][64 lanes][8]  (chunk c, tile t: B[k=c*32+(L>>4)*8+j][n=t*16+(L&15)])
// B2p: [128 kchunks][2 ntiles][64 lanes][8]
__global__ void prep_weights(const float* __restrict__ wss_s, const float* __restrict__ wvv_s,
                             const float* __restrict__ wss_g, const float* __restrict__ wvv_g,
                             const float* __restrict__ wsv,   const float* __restrict__ wvs,
                             __bf16* __restrict__ b1p, __bf16* __restrict__ b2p)
{
    int idx = blockIdx.x * 256 + threadIdx.x;
    const int N1 = 160 * 6 * 512;          // 491520
    const int N2 = 128 * 2 * 512;          // 131072
    if (idx < N1) {
        int j = idx & 7, L = (idx >> 3) & 63, ct = idx >> 9;
        int t = ct % 6, c = ct / 6;
        int k = c * 32 + (L >> 4) * 8 + j;
        int n = t * 16 + (L & 15);
        float val;
        if (k < 4096) { int u = k >> 6, v = k & 63, p = u * 64 + v;
            val = A_SS * (n < 64 ? wss_s[p * 64 + n] : wss_g[p * 32 + (n - 64)]);
        } else { int k2 = k - 4096; int u = k2 >> 5, v = k2 & 31, p = u * 32 + v;
            val = A_VV * (n < 64 ? wvv_s[p * 64 + n] : wvv_g[p * 32 + (n - 64)]);
        }
        b1p[idx] = (__bf16)val;
    } else if (idx < N1 + N2) {
        int id2 = idx - N1;
        int j = id2 & 7, L = (id2 >> 3) & 63, ct = id2 >> 9;
        int t = ct & 1, c = ct >> 1;
        int k = c * 32 + (L >> 4) * 8 + j;
        int n = t * 16 + (L & 15);
        float val;
        if (k < 2048) { int u = k >> 5, v = k & 31; val = wsv[(u * 32 + v) * 32 + n]; }
        else { int k2 = k - 2048; int u = k2 >> 6, v = k2 & 63; val = wvs[(u * 64 + v) * 32 + n]; }
        b2p[id2] = (__bf16)(A_SV * val);
    }
}

// ---------------- main kernel: 64 edges/block, 4 waves ----------------
// LDS: IN bf16 [64 e][328] (s1@0, s2@64, v1T@128 (i*32+v), v2T@224, pad) = 41984 B
//      zS bf16 [64][66] @41984 = 8448 B ; zG bf16 [64][34] @50432 = 4352 B  (total 54784)
//      ZV f32  [64][100] (i-stride 33) overlays IN after G2.
__global__ __launch_bounds__(256, 2)
void seconv_mfma(const float* __restrict__ fea1, const float* __restrict__ fea2,
                 const __bf16* __restrict__ b1p, const __bf16* __restrict__ b2p,
                 const float* __restrict__ wls, const float* __restrict__ wlv,
                 float* __restrict__ out, int E)
{
    __shared__ __align__(16) char smem[54784];
    __bf16* IN  = (__bf16*)smem;
    float*  ZV  = (float*)smem;
    __bf16* zSb = (__bf16*)(smem + 41984);
    __bf16* zGb = (__bf16*)(smem + 50432);

    const int tid  = threadIdx.x;
    const int lane = tid & 63;
    const int m    = lane & 15;
    const int quad = lane >> 4;
    const int w    = tid >> 6;
    const int h    = w & 1;       // edge half: e in [32h, 32h+32)
    const int nh   = w >> 1;      // G1 n-half (tiles 3nh..3nh+2); G2 n-tile
    const int tb   = nh * 3;
    const int t2   = nh;
    const int e0   = blockIdx.x * 64;

    // ---- stage inputs as bf16 (v-parts transposed to [i][v]) ----
    for (int i = tid; i < 64 * 160; i += 256) {
        int e = i / 160, c = i - e * 160;
        int ge = e0 + e; if (ge >= E) ge = E - 1;
        float a = fea1[ge * 160 + c];
        float b = fea2[ge * 160 + c];
        if (c < 64) { IN[e * 328 + c] = (__bf16)a; IN[e * 328 + 64 + c] = (__bf16)b; }
        else { int c2 = c - 64; int v = c2 / 3, ii = c2 - v * 3;
               IN[e * 328 + 128 + ii * 32 + v] = (__bf16)a;
               IN[e * 328 + 224 + ii * 32 + v] = (__bf16)b; }
    }
    __syncthreads();

    const int eA = h * 32 + m;        // strip 0 edge for this lane
    const int eB = h * 32 + 16 + m;   // strip 1 edge

    // ---- G1: acc[strip][ntile], K-loop over 160 chunks of B1p ----
    f32x4 acc[2][3];
    #pragma unroll
    for (int p = 0; p < 2; ++p)
        #pragma unroll
        for (int t = 0; t < 3; ++t) acc[p][t] = (f32x4){0.f, 0.f, 0.f, 0.f};

    // s2 fragments as fp32: [strip][half][j],  element = s2[e, half*32 + quad*8 + j]
    float s2f[2][2][8];
    #pragma unroll
    for (int p = 0; p < 2; ++p) {
        int e = p ? eB : eA;
        const __bf16* bptr = IN + e * 328 + 64 + quad * 8;
        bf16x8 lo = *(const bf16x8*)(bptr);
        bf16x8 hi = *(const bf16x8*)(bptr + 32);
        #pragma unroll
        for (int j = 0; j < 8; ++j) { s2f[p][0][j] = (float)lo[j]; s2f[p][1][j] = (float)hi[j]; }
    }

    f32x4 bcur[3], bnxt[3];
    #pragma unroll
    for (int t = 0; t < 3; ++t) bcur[t] = *(const f32x4*)(b1p + (((0 * 6) + tb + t) * 64 + lane) * 8);
    #pragma unroll
    for (int t = 0; t < 3; ++t) bnxt[t] = *(const f32x4*)(b1p + (((1 * 6) + tb + t) * 64 + lane) * 8);

    // P-part: chunks 0..127, chunk c = u*2+vh : A = s1[u] * s2[vh*32 + quad*8 + j]
    for (int u = 0; u < 64; ++u) {
        float s1A = (float)IN[eA * 328 + u];
        float s1B = (float)IN[eB * 328 + u];
        #pragma unroll
        for (int vh = 0; vh < 2; ++vh) {
            int c = u * 2 + vh;
            bf16x8 a0, a1;
            #pragma unroll
            for (int j = 0; j < 8; ++j) {
                a0[j] = (__bf16)(s1A * s2f[0][vh][j]);
                a1[j] = (__bf16)(s1B * s2f[1][vh][j]);
            }
            f32x4 b0 = bcur[0], b1 = bcur[1], b2 = bcur[2];
            #pragma unroll
            for (int t = 0; t < 3; ++t) bcur[t] = bnxt[t];
            int cn = c + 2;  // <= 129 < 160, always valid
            #pragma unroll
            for (int t = 0; t < 3; ++t)
                bnxt[t] = *(const f32x4*)(b1p + ((cn * 6 + tb + t) * 64 + lane) * 8);
            bf16x8 bb0 = __builtin_bit_cast(bf16x8, b0);
            bf16x8 bb1 = __builtin_bit_cast(bf16x8, b1);
            bf16x8 bb2 = __builtin_bit_cast(bf16x8, b2);
            acc[0][0] = MFMA16(a0, bb0, acc[0][0]);
            acc[0][1] = MFMA16(a0, bb1, acc[0][1]);
            acc[0][2] = MFMA16(a0, bb2, acc[0][2]);
            acc[1][0] = MFMA16(a1, bb0, acc[1][0]);
            acc[1][1] = MFMA16(a1, bb1, acc[1][1]);
            acc[1][2] = MFMA16(a1, bb2, acc[1][2]);
        }
    }

    // Q-part: chunks 128..159, chunk u: A = sum_i v1T[i][u] * v2T[i][quad*8+j]
    float v2f[2][3][8];
    #pragma unroll
    for (int p = 0; p < 2; ++p) {
        int e = p ? eB : eA;
        #pragma unroll
        for (int i3 = 0; i3 < 3; ++i3) {
            bf16x8 t = *(const bf16x8*)(IN + e * 328 + 224 + i3 * 32 + quad * 8);
            #pragma unroll
            for (int j = 0; j < 8; ++j) v2f[p][i3][j] = (float)t[j];
        }
    }
    for (int u = 0; u < 32; ++u) {
        int c = 128 + u;
        float v1A[3], v1B[3];
        #pragma unroll
        for (int i3 = 0; i3 < 3; ++i3) {
            v1A[i3] = (float)IN[eA * 328 + 128 + i3 * 32 + u];
            v1B[i3] = (float)IN[eB * 328 + 128 + i3 * 32 + u];
        }
        bf16x8 a0, a1;
        #pragma unroll
        for (int j = 0; j < 8; ++j) {
            float x0 = v1A[0] * v2f[0][0][j];
            x0 = fmaf(v1A[1], v2f[0][1][j], x0);
            x0 = fmaf(v1A[2], v2f[0][2][j], x0);
            float x1 = v1B[0] * v2f[1][0][j];
            x1 = fmaf(v1B[1], v2f[1][1][j], x1);
            x1 = fmaf(v1B[2], v2f[1][2][j], x1);
            a0[j] = (__bf16)x0; a1[j] = (__bf16)x1;
        }
        f32x4 b0 = bcur[0], b1 = bcur[1], b2 = bcur[2];
        #pragma unroll
        for (int t = 0; t < 3; ++t) bcur[t] = bnxt[t];
        int cn = c + 2; if (cn > 159) cn = 159;
        #pragma unroll
        for (int t = 0; t < 3; ++t)
            bnxt[t] = *(const f32x4*)(b1p + ((cn * 6 + tb + t) * 64 + lane) * 8);
        bf16x8 bb0 = __builtin_bit_cast(bf16x8, b0);
        bf16x8 bb1 = __builtin_bit_cast(bf16x8, b1);
        bf16x8 bb2 = __builtin_bit_cast(bf16x8, b2);
        acc[0][0] = MFMA16(a0, bb0, acc[0][0]);
        acc[0][1] = MFMA16(a0, bb1, acc[0][1]);
        acc[0][2] = MFMA16(a0, bb2, acc[0][2]);
        acc[1][0] = MFMA16(a1, bb0, acc[1][0]);
        acc[1][1] = MFMA16(a1, bb1, acc[1][1]);
        acc[1][2] = MFMA16(a1, bb2, acc[1][2]);
    }

    // write z (C-layout: col = lane&15 -> n, row = quad*4+r -> edge)
    #pragma unroll
    for (int p = 0; p < 2; ++p)
        #pragma unroll
        for (int t = 0; t < 3; ++t) {
            int n = (tb + t) * 16 + m;
            #pragma unroll
            for (int r = 0; r < 4; ++r) {
                int e_loc = h * 32 + p * 16 + quad * 4 + r;
                float z = acc[p][t][r];
                if (n < 64) zSb[e_loc * 66 + n] = (__bf16)z;
                else        zGb[e_loc * 34 + (n - 64)] = (__bf16)z;
            }
        }
    __syncthreads();

    // ---- G2: acc2[i][strip], K-loop over 128 chunks of B2p ----
    f32x4 acc2[3][2];
    #pragma unroll
    for (int i3 = 0; i3 < 3; ++i3)
        #pragma unroll
        for (int g = 0; g < 2; ++g) acc2[i3][g] = (f32x4){0.f, 0.f, 0.f, 0.f};

    f32x4 ccur = *(const f32x4*)(b2p + ((0 * 2 + t2) * 64 + lane) * 8);
    f32x4 cnxt = *(const f32x4*)(b2p + ((1 * 2 + t2) * 64 + lane) * 8);

    // sv-part: chunks 0..63, chunk u: A[(e,i)] = s1[u] * v2T[i][quad*8+j]
    for (int u = 0; u < 64; ++u) {
        float s1A = (float)IN[eA * 328 + u];
        float s1B = (float)IN[eB * 328 + u];
        bf16x8 a2[3][2];
        #pragma unroll
        for (int i3 = 0; i3 < 3; ++i3)
            #pragma unroll
            for (int j = 0; j < 8; ++j) {
                a2[i3][0][j] = (__bf16)(s1A * v2f[0][i3][j]);
                a2[i3][1][j] = (__bf16)(s1B * v2f[1][i3][j]);
            }
        f32x4 cb = ccur; ccur = cnxt;
        int cn = u + 2; if (cn > 127) cn = 127;
        cnxt = *(const f32x4*)(b2p + ((cn * 2 + t2) * 64 + lane) * 8);
        bf16x8 bb = __builtin_bit_cast(bf16x8, cb);
        #pragma unroll
        for (int i3 = 0; i3 < 3; ++i3) {
            acc2[i3][0] = MFMA16(a2[i3][0], bb, acc2[i3][0]);
            acc2[i3][1] = MFMA16(a2[i3][1], bb, acc2[i3][1]);
        }
    }
    // vs-part: chunks 64..127, chunk c=64+uu*2+vh: A[(e,i)] = v1T[i][uu] * s2[vh*32+quad*8+j]
    for (int uu = 0; uu < 32; ++uu) {
        float v1A[3], v1B[3];
        #pragma unroll
        for (int i3 = 0; i3 < 3; ++i3) {
            v1A[i3] = (float)IN[eA * 328 + 128 + i3 * 32 + uu];
            v1B[i3] = (float)IN[eB * 328 + 128 + i3 * 32 + uu];
        }
        #pragma unroll
        for (int vh = 0; vh < 2; ++vh) {
            int c = 64 + uu * 2 + vh;
            bf16x8 a2[3][2];
            #pragma unroll
            for (int i3 = 0; i3 < 3; ++i3)
                #pragma unroll
                for (int j = 0; j < 8; ++j) {
                    a2[i3][0][j] = (__bf16)(v1A[i3] * s2f[0][vh][j]);
                    a2[i3][1][j] = (__bf16)(v1B[i3] * s2f[1][vh][j]);
                }
            f32x4 cb = ccur; ccur = cnxt;
            int cn = c + 2; if (cn > 127) cn = 127;
            cnxt = *(const f32x4*)(b2p + ((cn * 2 + t2) * 64 + lane) * 8);
            bf16x8 bb = __builtin_bit_cast(bf16x8, cb);
            #pragma unroll
            for (int i3 = 0; i3 < 3; ++i3) {
                acc2[i3][0] = MFMA16(a2[i3][0], bb, acc2[i3][0]);
                acc2[i3][1] = MFMA16(a2[i3][1], bb, acc2[i3][1]);
            }
        }
    }
    __syncthreads();   // all waves done reading IN; safe to overlay ZV

    // gate + store z_v (ZV[e][i*33 + v], e-stride 100 floats)
    #pragma unroll
    for (int i3 = 0; i3 < 3; ++i3)
        #pragma unroll
        for (int g = 0; g < 2; ++g)
            #pragma unroll
            for (int r = 0; r < 4; ++r) {
                int e_loc = h * 32 + g * 16 + quad * 4 + r;
                int v = t2 * 16 + m;
                float zg = (float)zGb[e_loc * 34 + v];
                float gate = 1.f / (1.f + __expf(-zg));
                ZV[e_loc * 100 + i3 * 33 + v] = gate * acc2[i3][g][r];
            }
    // silu on zS (in place, bf16)
    for (int i = tid; i < 64 * 64; i += 256) {
        int e = i >> 6, n = i & 63;
        float z = (float)zSb[e * 66 + n];
        zSb[e * 66 + n] = (__bf16)(z / (1.f + __expf(-z)));
    }
    __syncthreads();

    // ---- epilogue output GEMMs (fp32 VALU) ----
    for (int i = tid; i < 64 * 64; i += 256) {
        int e = i >> 6, wo = i & 63;
        int ge = e0 + e;
        float a = 0.f;
        #pragma unroll 8
        for (int ww = 0; ww < 64; ++ww)
            a = fmaf((float)zSb[e * 66 + ww], wls[ww * 64 + wo], a);
        if (ge < E) out[ge * 160 + wo] = 0.125f * a;
    }
    for (int i = tid; i < 64 * 96; i += 256) {
        int e = i / 96, tq = i - e * 96;
        int wo = tq / 3, i3 = tq - wo * 3;
        int ge = e0 + e;
        float a = 0.f;
        #pragma unroll 8
        for (int v = 0; v < 32; ++v)
            a = fmaf(ZV[e * 100 + i3 * 33 + v], wlv[v * 32 + wo], a);
        if (ge < E) out[ge * 160 + 64 + tq] = 0.1767766952966369f * a;
    }
}

extern "C" void kernel_launch(void* const* d_in, const int* in_sizes, int n_in,
                              void* d_out, int out_size, void* d_ws, size_t ws_size,
                              hipStream_t stream) {
    const float* fea1  = (const float*)d_in[0];
    const float* fea2  = (const float*)d_in[1];
    const float* wss_s = (const float*)d_in[4];
    const float* wvv_s = (const float*)d_in[5];
    const float* wss_g = (const float*)d_in[6];
    const float* wvv_g = (const float*)d_in[7];
    const float* wsv   = (const float*)d_in[8];
    const float* wvs   = (const float*)d_in[9];
    const float* wls   = (const float*)d_in[10];
    const float* wlv   = (const float*)d_in[11];
    float* out = (float*)d_out;

    __bf16* b1p = (__bf16*)d_ws;                          // 983040 B
    __bf16* b2p = (__bf16*)((char*)d_ws + 983040);        // 262144 B

    int E = in_sizes[0] / 160;   // 100000
    prep_weights<<<dim3(2432), dim3(256), 0, stream>>>(wss_s, wvv_s, wss_g, wvv_g, wsv, wvs, b1p, b2p);
    int grid = (E + 63) / 64;    // 1563
    seconv_mfma<<<dim3(grid), dim3(256), 0, stream>>>(fea1, fea2, b1p, b2p, wls, wlv, out, E);
}

// Round 3
// 509.019 us; speedup vs baseline: 11.1038x; 1.3651x over previous
//
#include <hip/hip_runtime.h>

// SelfEquiConv E=100000, S=64, V=32 — f16 MFMA formulation (round 3).
// G1: [z_s|z_g] = A1 @ B1, A1[e,k] = {A_SS*s1 s2 | A_VV*<v1,v2>}, K=5120, N=96
// G2: z_v = A2 @ B2, rows (e,i), K=4096, N=32; wave = (e-half, K-half), partials via LDS.
// Epilogue: silu/sigmoid in f32 VALU, output GEMMs (wl_s, wl_v) as f16 MFMA.
// All A-fragments built with packed f16 math (v_pk_mul/fma_f16) — no cvt in hot loops.

typedef _Float16 f16;
typedef _Float16 f16x8 __attribute__((ext_vector_type(8)));
typedef float    f32x4 __attribute__((ext_vector_type(4)));

constexpr float A_SS  = 0.011048543456039806f; // (2*64*64)^-0.5  == A_SS_G
constexpr float A_VV  = 0.012757759747374832f; // (2*32*32*3)^-0.5 == A_VV_G
constexpr float A_SV  = 0.009021097956087904f; // (2*64*32*3)^-0.5 == A_VS_V
constexpr float SO_SC = 0.125f;                // 64^-0.5
constexpr float VO_SC = 0.1767766952966369f;   // 32^-0.5

#define MFMA16(A, B, C) __builtin_amdgcn_mfma_f32_16x16x32_f16((A), (B), (C), 0, 0, 0)

static __device__ __forceinline__ f16x8 splat8(f16 x) {
    return (f16x8){x, x, x, x, x, x, x, x};
}

// ---------------- prep: swizzle weights into MFMA B-fragment order (f16) ----------------
// b1p:  [160 kchunks][6 t][64 L][8]   k=c*32+(L>>4)*8+j, n=t*16+(L&15)
// b2p:  [128 kchunks][2 t][64 L][8]
// wlsP: [2 kc][4 t][64 L][8]          k=kc*32+(L>>4)*8+j (zS channel), n=t*16+(L&15), *SO_SC
// wlvP: [2 t][64 L][8]                k=(L>>4)*8+j (v),                n=t*16+(L&15), *VO_SC
__global__ void prep_weights(const float* __restrict__ wss_s, const float* __restrict__ wvv_s,
                             const float* __restrict__ wss_g, const float* __restrict__ wvv_g,
                             const float* __restrict__ wsv,   const float* __restrict__ wvs,
                             const float* __restrict__ wls,   const float* __restrict__ wlv,
                             f16* __restrict__ b1p, f16* __restrict__ b2p,
                             f16* __restrict__ wlsP, f16* __restrict__ wlvP)
{
    int idx = blockIdx.x * 256 + threadIdx.x;
    const int N1 = 160 * 6 * 512;          // 491520
    const int N2 = 128 * 2 * 512;          // 131072
    const int N3 = 8 * 512;                // 4096
    const int N4 = 2 * 512;                // 1024
    if (idx < N1) {
        int j = idx & 7, L = (idx >> 3) & 63, ct = idx >> 9;
        int t = ct % 6, c = ct / 6;
        int k = c * 32 + (L >> 4) * 8 + j;
        int n = t * 16 + (L & 15);
        float val;
        if (k < 4096) { int u = k >> 6, v = k & 63, p = u * 64 + v;
            val = A_SS * (n < 64 ? wss_s[p * 64 + n] : wss_g[p * 32 + (n - 64)]);
        } else { int k2 = k - 4096; int u = k2 >> 5, v = k2 & 31, p = u * 32 + v;
            val = A_VV * (n < 64 ? wvv_s[p * 64 + n] : wvv_g[p * 32 + (n - 64)]);
        }
        b1p[idx] = (f16)val;
    } else if (idx < N1 + N2) {
        int id2 = idx - N1;
        int j = id2 & 7, L = (id2 >> 3) & 63, ct = id2 >> 9;
        int t = ct & 1, c = ct >> 1;
        int k = c * 32 + (L >> 4) * 8 + j;
        int n = t * 16 + (L & 15);
        float val;
        if (k < 2048) { int u = k >> 5, v = k & 31; val = wsv[(u * 32 + v) * 32 + n]; }
        else { int k2 = k - 2048; int u = k2 >> 6, v = k2 & 63; val = wvs[(u * 64 + v) * 32 + n]; }
        b2p[id2] = (f16)(A_SV * val);
    } else if (idx < N1 + N2 + N3) {
        int id3 = idx - N1 - N2;
        int j = id3 & 7, L = (id3 >> 3) & 63, ct = id3 >> 9;   // ct in [0,8)
        int t = ct & 3, kc = ct >> 2;
        int k = kc * 32 + (L >> 4) * 8 + j;
        int n = t * 16 + (L & 15);
        wlsP[id3] = (f16)(SO_SC * wls[k * 64 + n]);
    } else if (idx < N1 + N2 + N3 + N4) {
        int id4 = idx - N1 - N2 - N3;
        int j = id4 & 7, L = (id4 >> 3) & 63, t = id4 >> 9;    // t in [0,2)
        int k = (L >> 4) * 8 + j;
        int n = t * 16 + (L & 15);
        wlvP[id4] = (f16)(VO_SC * wlv[k * 32 + n]);
    }
}

// ---------------- main kernel: 64 edges/block, 4 waves ----------------
// smem map (bytes):
//   [0, 41984)     IN f16 [64][328]: s1@0, s2@64, v1T@128 (i*32+v), v2T@224
//                  later overlays: ZVP f32 [3*64][33] @0 (25344); ZVH f16 [3*64][40] @25600 (15360)
//                  then: OUTV f32 [64][100] @0 (25600)  (ZVH @25600 stays live alongside)
//   [41984, 52224) zS f16 [64][80]
//   [52224, 56576) zG f16 [64][34]
__global__ __launch_bounds__(256, 2)
void seconv_mfma(const float* __restrict__ fea1, const float* __restrict__ fea2,
                 const f16* __restrict__ b1p, const f16* __restrict__ b2p,
                 const f16* __restrict__ wlsP, const f16* __restrict__ wlvP,
                 float* __restrict__ out, int E)
{
    __shared__ __align__(16) char smem[56576];
    f16*   IN   = (f16*)smem;
    float* ZVP  = (float*)smem;
    f16*   ZVH  = (f16*)(smem + 25600);
    float* OUTV = (float*)smem;
    f16*   zSh  = (f16*)(smem + 41984);
    f16*   zGh  = (f16*)(smem + 52224);

    const int tid  = threadIdx.x;
    const int lane = tid & 63;
    const int m    = lane & 15;
    const int quad = lane >> 4;
    const int w    = tid >> 6;
    const int h    = w & 1;       // edge half: e in [32h, 32h+32)
    const int nh   = w >> 1;      // G1: n-half (tiles 3nh..3nh+2)
    const int kh   = w >> 1;      // G2: K-half
    const int tb   = nh * 3;
    const int e0   = blockIdx.x * 64;

    // ---- stage inputs as f16 (v-parts transposed to [i][v]) ----
    for (int i = tid; i < 64 * 160; i += 256) {
        int e = i / 160, c = i - e * 160;
        int ge = e0 + e; if (ge >= E) ge = E - 1;
        float a = fea1[ge * 160 + c];
        float b = fea2[ge * 160 + c];
        if (c < 64) { IN[e * 328 + c] = (f16)a; IN[e * 328 + 64 + c] = (f16)b; }
        else { int c2 = c - 64; int v = c2 / 3, ii = c2 - v * 3;
               IN[e * 328 + 128 + ii * 32 + v] = (f16)a;
               IN[e * 328 + 224 + ii * 32 + v] = (f16)b; }
    }
    __syncthreads();

    const int eA = h * 32 + m;        // strip p=0 edge for this lane
    const int eB = h * 32 + 16 + m;   // strip p=1 edge

    // fragment preloads (f16x8, 16B-aligned): s2 and v2T for both strips
    f16x8 s2q[2][2], v2q[2][3];
    #pragma unroll
    for (int p = 0; p < 2; ++p) {
        int e = p ? eB : eA;
        #pragma unroll
        for (int vh = 0; vh < 2; ++vh)
            s2q[p][vh] = *(const f16x8*)(IN + e * 328 + 64 + vh * 32 + quad * 8);
        #pragma unroll
        for (int i3 = 0; i3 < 3; ++i3)
            v2q[p][i3] = *(const f16x8*)(IN + e * 328 + 224 + i3 * 32 + quad * 8);
    }

    // ================= G1: [z_s|z_g], 160 kchunks =================
    f32x4 acc[2][3];
    #pragma unroll
    for (int p = 0; p < 2; ++p)
        #pragma unroll
        for (int t = 0; t < 3; ++t) acc[p][t] = (f32x4){0.f, 0.f, 0.f, 0.f};

    f32x4 bcur[3], bnxt[3];
    #pragma unroll
    for (int t = 0; t < 3; ++t) bcur[t] = *(const f32x4*)(b1p + ((0 * 6 + tb + t) * 64 + lane) * 8);
    #pragma unroll
    for (int t = 0; t < 3; ++t) bnxt[t] = *(const f32x4*)(b1p + ((1 * 6 + tb + t) * 64 + lane) * 8);

    // P-part: chunks 0..127, chunk = u*2+vh: A = s1[u]*s2[vh*32+quad*8+j]
    for (int u = 0; u < 64; ++u) {
        f16x8 s1A = splat8(IN[eA * 328 + u]);
        f16x8 s1B = splat8(IN[eB * 328 + u]);
        #pragma unroll
        for (int vh = 0; vh < 2; ++vh) {
            int c = u * 2 + vh;
            f16x8 a0 = s1A * s2q[0][vh];
            f16x8 a1 = s1B * s2q[1][vh];
            f32x4 b0 = bcur[0], b1 = bcur[1], b2 = bcur[2];
            #pragma unroll
            for (int t = 0; t < 3; ++t) bcur[t] = bnxt[t];
            int cn = c + 2;                       // <=129, always valid
            #pragma unroll
            for (int t = 0; t < 3; ++t)
                bnxt[t] = *(const f32x4*)(b1p + ((cn * 6 + tb + t) * 64 + lane) * 8);
            f16x8 bb0 = __builtin_bit_cast(f16x8, b0);
            f16x8 bb1 = __builtin_bit_cast(f16x8, b1);
            f16x8 bb2 = __builtin_bit_cast(f16x8, b2);
            acc[0][0] = MFMA16(a0, bb0, acc[0][0]);
            acc[0][1] = MFMA16(a0, bb1, acc[0][1]);
            acc[0][2] = MFMA16(a0, bb2, acc[0][2]);
            acc[1][0] = MFMA16(a1, bb0, acc[1][0]);
            acc[1][1] = MFMA16(a1, bb1, acc[1][1]);
            acc[1][2] = MFMA16(a1, bb2, acc[1][2]);
        }
    }
    // Q-part: chunks 128..159, chunk u: A = sum_i v1T[i][u]*v2T[i][quad*8+j]
    for (int u = 0; u < 32; ++u) {
        int c = 128 + u;
        f16x8 a0, a1;
        {
            f16 x0 = IN[eA * 328 + 128 + 0 * 32 + u];
            f16 x1 = IN[eA * 328 + 128 + 1 * 32 + u];
            f16 x2 = IN[eA * 328 + 128 + 2 * 32 + u];
            a0 = splat8(x0) * v2q[0][0];
            a0 += splat8(x1) * v2q[0][1];
            a0 += splat8(x2) * v2q[0][2];
            f16 y0 = IN[eB * 328 + 128 + 0 * 32 + u];
            f16 y1 = IN[eB * 328 + 128 + 1 * 32 + u];
            f16 y2 = IN[eB * 328 + 128 + 2 * 32 + u];
            a1 = splat8(y0) * v2q[1][0];
            a1 += splat8(y1) * v2q[1][1];
            a1 += splat8(y2) * v2q[1][2];
        }
        f32x4 b0 = bcur[0], b1 = bcur[1], b2 = bcur[2];
        #pragma unroll
        for (int t = 0; t < 3; ++t) bcur[t] = bnxt[t];
        int cn = c + 2; if (cn > 159) cn = 159;
        #pragma unroll
        for (int t = 0; t < 3; ++t)
            bnxt[t] = *(const f32x4*)(b1p + ((cn * 6 + tb + t) * 64 + lane) * 8);
        f16x8 bb0 = __builtin_bit_cast(f16x8, b0);
        f16x8 bb1 = __builtin_bit_cast(f16x8, b1);
        f16x8 bb2 = __builtin_bit_cast(f16x8, b2);
        acc[0][0] = MFMA16(a0, bb0, acc[0][0]);
        acc[0][1] = MFMA16(a0, bb1, acc[0][1]);
        acc[0][2] = MFMA16(a0, bb2, acc[0][2]);
        acc[1][0] = MFMA16(a1, bb0, acc[1][0]);
        acc[1][1] = MFMA16(a1, bb1, acc[1][1]);
        acc[1][2] = MFMA16(a1, bb2, acc[1][2]);
    }

    // z write (C-layout: col=m -> n, row=quad*4+r -> edge)
    #pragma unroll
    for (int p = 0; p < 2; ++p)
        #pragma unroll
        for (int t = 0; t < 3; ++t) {
            int n = (tb + t) * 16 + m;
            #pragma unroll
            for (int r = 0; r < 4; ++r) {
                int e_loc = h * 32 + p * 16 + quad * 4 + r;
                float z = acc[p][t][r];
                if (n < 64) zSh[e_loc * 80 + n] = (f16)z;
                else        zGh[e_loc * 34 + (n - 64)] = (f16)z;
            }
        }

    // ================= G2: z_v, rows (e,i), wave = (h, kh) =================
    f32x4 acc2[3][2][2];   // [i][p][t]
    #pragma unroll
    for (int i3 = 0; i3 < 3; ++i3)
        #pragma unroll
        for (int p = 0; p < 2; ++p)
            #pragma unroll
            for (int t = 0; t < 2; ++t) acc2[i3][p][t] = (f32x4){0.f, 0.f, 0.f, 0.f};

    // wave's chunk sequence: [kh*32 .. +31] then [64+kh*32 .. +31]
    auto c_of = [&](int s) { if (s > 63) s = 63; return (s < 32) ? (kh * 32 + s) : (32 + kh * 32 + s); };
    f32x4 q0 = *(const f32x4*)(b2p + ((c_of(0) * 2 + 0) * 64 + lane) * 8);
    f32x4 q1 = *(const f32x4*)(b2p + ((c_of(0) * 2 + 1) * 64 + lane) * 8);
    f32x4 r0 = *(const f32x4*)(b2p + ((c_of(1) * 2 + 0) * 64 + lane) * 8);
    f32x4 r1 = *(const f32x4*)(b2p + ((c_of(1) * 2 + 1) * 64 + lane) * 8);
    int sq = 0;

    // sv phase: chunk u: A[(e,i)] = s1[u] * v2T[i][quad*8+j]
    for (int cc = 0; cc < 32; ++cc, ++sq) {
        int u = kh * 32 + cc;
        f16x8 s1A = splat8(IN[eA * 328 + u]);
        f16x8 s1B = splat8(IN[eB * 328 + u]);
        f16x8 bb0 = __builtin_bit_cast(f16x8, q0);
        f16x8 bb1 = __builtin_bit_cast(f16x8, q1);
        q0 = r0; q1 = r1;
        int cn = c_of(sq + 2);
        r0 = *(const f32x4*)(b2p + ((cn * 2 + 0) * 64 + lane) * 8);
        r1 = *(const f32x4*)(b2p + ((cn * 2 + 1) * 64 + lane) * 8);
        #pragma unroll
        for (int i3 = 0; i3 < 3; ++i3) {
            f16x8 aA = s1A * v2q[0][i3];
            f16x8 aB = s1B * v2q[1][i3];
            acc2[i3][0][0] = MFMA16(aA, bb0, acc2[i3][0][0]);
            acc2[i3][0][1] = MFMA16(aA, bb1, acc2[i3][0][1]);
            acc2[i3][1][0] = MFMA16(aB, bb0, acc2[i3][1][0]);
            acc2[i3][1][1] = MFMA16(aB, bb1, acc2[i3][1][1]);
        }
    }
    // vs phase: chunk 64+u*2+vh: A[(e,i)] = v1T[i][u] * s2[vh*32+quad*8+j]
    for (int uu = 0; uu < 16; ++uu) {
        int u = kh * 16 + uu;
        f16 v1A[3], v1B[3];
        #pragma unroll
        for (int i3 = 0; i3 < 3; ++i3) {
            v1A[i3] = IN[eA * 328 + 128 + i3 * 32 + u];
            v1B[i3] = IN[eB * 328 + 128 + i3 * 32 + u];
        }
        #pragma unroll
        for (int vh = 0; vh < 2; ++vh, ++sq) {
            f16x8 bb0 = __builtin_bit_cast(f16x8, q0);
            f16x8 bb1 = __builtin_bit_cast(f16x8, q1);
            q0 = r0; q1 = r1;
            int cn = c_of(sq + 2);
            r0 = *(const f32x4*)(b2p + ((cn * 2 + 0) * 64 + lane) * 8);
            r1 = *(const f32x4*)(b2p + ((cn * 2 + 1) * 64 + lane) * 8);
            #pragma unroll
            for (int i3 = 0; i3 < 3; ++i3) {
                f16x8 aA = splat8(v1A[i3]) * s2q[0][vh];
                f16x8 aB = splat8(v1B[i3]) * s2q[1][vh];
                acc2[i3][0][0] = MFMA16(aA, bb0, acc2[i3][0][0]);
                acc2[i3][0][1] = MFMA16(aA, bb1, acc2[i3][0][1]);
                acc2[i3][1][0] = MFMA16(aB, bb0, acc2[i3][1][0]);
                acc2[i3][1][1] = MFMA16(aB, bb1, acc2[i3][1][1]);
            }
        }
    }
    __syncthreads();   // all IN reads done

    // ---- merge K-halves: kh=0 writes partials (overlay IN); kh=1 does silu ----
    if (kh == 0) {
        #pragma unroll
        for (int i3 = 0; i3 < 3; ++i3)
            #pragma unroll
            for (int p = 0; p < 2; ++p)
                #pragma unroll
                for (int t = 0; t < 2; ++t)
                    #pragma unroll
                    for (int r = 0; r < 4; ++r) {
                        int e_loc = h * 32 + p * 16 + quad * 4 + r;
                        ZVP[(i3 * 64 + e_loc) * 33 + t * 16 + m] = acc2[i3][p][t][r];
                    }
    } else {
        for (int i = tid - 128; i < 64 * 64; i += 128) {   // kh=1 waves: tid in [128,256)
            int e = i >> 6, n = i & 63;
            float z = (float)zSh[e * 80 + n];
            zSh[e * 80 + n] = (f16)(z / (1.f + __expf(-z)));
        }
    }
    __syncthreads();

    if (kh == 1) {   // add partials, gate, store ZVH (f16)
        #pragma unroll
        for (int i3 = 0; i3 < 3; ++i3)
            #pragma unroll
            for (int p = 0; p < 2; ++p)
                #pragma unroll
                for (int t = 0; t < 2; ++t)
                    #pragma unroll
                    for (int r = 0; r < 4; ++r) {
                        int e_loc = h * 32 + p * 16 + quad * 4 + r;
                        float zv = acc2[i3][p][t][r] + ZVP[(i3 * 64 + e_loc) * 33 + t * 16 + m];
                        float zg = (float)zGh[e_loc * 34 + t * 16 + m];
                        float gate = 1.f / (1.f + __expf(-zg));
                        ZVH[(i3 * 64 + e_loc) * 40 + t * 16 + m] = (f16)(gate * zv);
                    }
    }
    __syncthreads();

    // ================= epilogue GEMMs (f16 MFMA) =================
    // GEMM-S: out_s[64][64] = silu(zS) @ wlsP ; wave w owns m-strip w, all 4 n-tiles
    {
        f32x4 accS[4];
        #pragma unroll
        for (int t = 0; t < 4; ++t) accS[t] = (f32x4){0.f, 0.f, 0.f, 0.f};
        #pragma unroll
        for (int kc = 0; kc < 2; ++kc) {
            f16x8 aS = *(const f16x8*)(zSh + (w * 16 + m) * 80 + kc * 32 + quad * 8);
            #pragma unroll
            for (int t = 0; t < 4; ++t) {
                f32x4 braw = *(const f32x4*)(wlsP + ((kc * 4 + t) * 64 + lane) * 8);
                accS[t] = MFMA16(aS, __builtin_bit_cast(f16x8, braw), accS[t]);
            }
        }
        #pragma unroll
        for (int t = 0; t < 4; ++t)
            #pragma unroll
            for (int r = 0; r < 4; ++r) {
                int ge = e0 + w * 16 + quad * 4 + r;
                if (ge < E) out[ge * 160 + t * 16 + m] = accS[t][r];
            }
    }
    // GEMM-V: out_v rows (i,e) = gated z_v @ wlvP ; wave w owns e-strip w, i=0..2, 2 n-tiles
    {
        f32x4 accV[3][2];
        #pragma unroll
        for (int i3 = 0; i3 < 3; ++i3)
            #pragma unroll
            for (int t = 0; t < 2; ++t) accV[i3][t] = (f32x4){0.f, 0.f, 0.f, 0.f};
        f16x8 bV[2];
        #pragma unroll
        for (int t = 0; t < 2; ++t) {
            f32x4 braw = *(const f32x4*)(wlvP + (t * 64 + lane) * 8);
            bV[t] = __builtin_bit_cast(f16x8, braw);
        }
        #pragma unroll
        for (int i3 = 0; i3 < 3; ++i3) {
            f16x8 aV = *(const f16x8*)(ZVH + (i3 * 64 + w * 16 + m) * 40 + quad * 8);
            #pragma unroll
            for (int t = 0; t < 2; ++t) accV[i3][t] = MFMA16(aV, bV[t], accV[i3][t]);
        }
        __syncthreads();   // ZVP (overlapping OUTV region) fully consumed above
        #pragma unroll
        for (int i3 = 0; i3 < 3; ++i3)
            #pragma unroll
            for (int t = 0; t < 2; ++t)
                #pragma unroll
                for (int r = 0; r < 4; ++r) {
                    int e_loc = w * 16 + quad * 4 + r;
                    OUTV[e_loc * 100 + (t * 16 + m) * 3 + i3] = accV[i3][t][r];
                }
    }
    __syncthreads();

    // coalesced v-part store
    for (int i = tid; i < 64 * 96; i += 256) {
        int e = i / 96, c = i - e * 96;
        int ge = e0 + e;
        if (ge < E) out[ge * 160 + 64 + c] = OUTV[e * 100 + c];
    }
}

extern "C" void kernel_launch(void* const* d_in, const int* in_sizes, int n_in,
                              void* d_out, int out_size, void* d_ws, size_t ws_size,
                              hipStream_t stream) {
    const float* fea1  = (const float*)d_in[0];
    const float* fea2  = (const float*)d_in[1];
    const float* wss_s = (const float*)d_in[4];
    const float* wvv_s = (const float*)d_in[5];
    const float* wss_g = (const float*)d_in[6];
    const float* wvv_g = (const float*)d_in[7];
    const float* wsv   = (const float*)d_in[8];
    const float* wvs   = (const float*)d_in[9];
    const float* wls   = (const float*)d_in[10];
    const float* wlv   = (const float*)d_in[11];
    float* out = (float*)d_out;

    f16* b1p  = (f16*)d_ws;                               // 983040 B
    f16* b2p  = (f16*)((char*)d_ws + 983040);             // 262144 B
    f16* wlsP = (f16*)((char*)d_ws + 1245184);            // 8192 B
    f16* wlvP = (f16*)((char*)d_ws + 1253376);            // 2048 B

    int E = in_sizes[0] / 160;   // 100000
    int prep_total = 491520 + 131072 + 4096 + 1024;       // 627712
    prep_weights<<<dim3((prep_total + 255) / 256), dim3(256), 0, stream>>>(
        wss_s, wvv_s, wss_g, wvv_g, wsv, wvs, wls, wlv, b1p, b2p, wlsP, wlvP);
    int grid = (E + 63) / 64;    // 1563
    seconv_mfma<<<dim3(grid), dim3(256), 0, stream>>>(
        fea1, fea2, b1p, b2p, wlsP, wlvP, out, E);
}